// Round 4
// baseline (148.234 us; speedup 1.0000x reference)
//
#include <hip/hip_runtime.h>

#define N 8000
#define SEQ 200
#define MAX_STEPS 199

#define NBLOCKS 2048                    // block 0 = loss, 1..2047 = regularizer
#define NTHREADS 256
#define REG_T (2047 * NTHREADS)         // 524,032 reg threads
#define NN4 16000000                    // N*N/4 float4 per matrix
// strides of REG_T f4: 30 full (0..29) + 1 partial (30); 7 quad-iters cover 0..27
#define QUAD_ITERS 7

typedef float f4 __attribute__((ext_vector_type(4)));

__device__ __forceinline__ float log_sum4(f4 v) {
    // log(|x|+1) = ln2 * log2(|x|+1); ln2*0.5 folded into the final atomic.
    return __log2f(fabsf(v[0]) + 1.0f) + __log2f(fabsf(v[1]) + 1.0f) +
           __log2f(fabsf(v[2]) + 1.0f) + __log2f(fabsf(v[3]) + 1.0f);
}

__global__ void __launch_bounds__(NTHREADS)
k_fused(const int* __restrict__ a,
        const float* __restrict__ s,
        const float* __restrict__ pe,
        const float* __restrict__ ne,
        const float* __restrict__ kp,
        float* __restrict__ out) {
    __shared__ float wsum[NTHREADS / 64];
    const int tid = threadIdx.x;

    if (blockIdx.x == 0) {
        // ------------------- sequential loss (1 block, hidden under reg) ----
        __shared__ int   sa[MAX_STEPS];
        __shared__ float ss[MAX_STEPS];
        for (int i = tid; i < MAX_STEPS; i += NTHREADS) {
            sa[i] = a[i];
            ss[i] = s[i];
        }
        __syncthreads();

        __shared__ int V;
        if (tid == 0) {
            int v = MAX_STEPS;
            for (int t = 0; t < MAX_STEPS; ++t)
                if (ss[t] < 0.0f) { v = t; break; }
            V = v;
        }
        __syncthreads();

        float li = 0.0f;
        if (tid < MAX_STEPS && tid < V) {
            const int j = sa[tid];
            float k = kp[j];
            int t = 0;
            // batched-8 prefetch: loads are independent of the fold chain
            for (; t + 8 <= tid; t += 8) {
                float pv[8], nv[8];
                #pragma unroll
                for (int u = 0; u < 8; ++u) {
                    size_t off = (size_t)sa[t + u] * N + (size_t)j;
                    pv[u] = pe[off];
                    nv[u] = ne[off];
                }
                #pragma unroll
                for (int u = 0; u < 8; ++u) {
                    float st = ss[t + u];
                    float d = st * pv[u] + (1.0f - st) * nv[u];
                    k = fminf(fmaxf(k + d, -30.0f), 30.0f);
                }
            }
            for (; t < tid; ++t) {
                float st = ss[t];
                size_t off = (size_t)sa[t] * N + (size_t)j;
                float d = st * pe[off] + (1.0f - st) * ne[off];
                k = fminf(fmaxf(k + d, -30.0f), 30.0f);
            }
            float p = fminf(fmaxf(k, 0.01f), 0.99f);
            li = -(ss[tid] * logf(p) + (1.0f - ss[tid]) * logf(1.0f - p));
        }

        #pragma unroll
        for (int o = 32; o > 0; o >>= 1) li += __shfl_down(li, o);
        if ((tid & 63) == 0) wsum[tid >> 6] = li;
        __syncthreads();
        if (tid == 0) {
            float total = 0.0f;
            #pragma unroll
            for (int w = 0; w < NTHREADS / 64; ++w) total += wsum[w];
            atomicAdd(out, total);
        }
        return;
    }

    // ----------------------- regularizer (2047 blocks) ----------------------
    const f4* __restrict__ pe4 = (const f4*)pe;
    const f4* __restrict__ ne4 = (const f4*)ne;
    const int rt = (int)(blockIdx.x - 1) * NTHREADS + tid;   // 0 .. REG_T-1

    float acc = 0.0f;

    // 7 iterations x 4 strides, 8 dwordx4 loads in flight per iteration
    #pragma unroll 1
    for (int it = 0; it < QUAD_ITERS; ++it) {
        size_t base = (size_t)rt + (size_t)(it * 4) * REG_T;
        f4 p0 = pe4[base];
        f4 p1 = pe4[base + (size_t)REG_T];
        f4 p2 = pe4[base + (size_t)2 * REG_T];
        f4 p3 = pe4[base + (size_t)3 * REG_T];
        f4 n0 = ne4[base];
        f4 n1 = ne4[base + (size_t)REG_T];
        f4 n2 = ne4[base + (size_t)2 * REG_T];
        f4 n3 = ne4[base + (size_t)3 * REG_T];
        acc += log_sum4(p0);
        acc += log_sum4(p1);
        acc += log_sum4(p2);
        acc += log_sum4(p3);
        acc += log_sum4(n0);
        acc += log_sum4(n1);
        acc += log_sum4(n2);
        acc += log_sum4(n3);
    }
    // strides 28, 29 (full)
    {
        size_t p28 = (size_t)rt + (size_t)28 * REG_T;
        size_t p29 = (size_t)rt + (size_t)29 * REG_T;
        f4 a0 = pe4[p28];
        f4 a1 = pe4[p29];
        f4 b0 = ne4[p28];
        f4 b1 = ne4[p29];
        acc += log_sum4(a0);
        acc += log_sum4(a1);
        acc += log_sum4(b0);
        acc += log_sum4(b1);
    }
    // stride 30 (partial: rt < 279,040)
    {
        size_t p = (size_t)rt + (size_t)30 * REG_T;
        if (p < (size_t)NN4) {
            f4 a0 = pe4[p];
            f4 b0 = ne4[p];
            acc += log_sum4(a0);
            acc += log_sum4(b0);
        }
    }

    // wave64 reduce + block reduce
    #pragma unroll
    for (int o = 32; o > 0; o >>= 1) acc += __shfl_down(acc, o);
    if ((tid & 63) == 0) wsum[tid >> 6] = acc;
    __syncthreads();
    if (tid == 0) {
        float b = 0.0f;
        #pragma unroll
        for (int w = 0; w < NTHREADS / 64; ++w) b += wsum[w];
        // 0.5 * ln(2): log2 -> ln conversion + the 0.5 regularizer factor
        atomicAdd(out, 0.34657359027997264f * b);
    }
}

extern "C" void kernel_launch(void* const* d_in, const int* in_sizes, int n_in,
                              void* d_out, int out_size, void* d_ws, size_t ws_size,
                              hipStream_t stream) {
    const int*   a  = (const int*)d_in[0];
    const float* s  = (const float*)d_in[1];
    const float* pe = (const float*)d_in[2];
    const float* ne = (const float*)d_in[3];
    const float* kp = (const float*)d_in[4];
    float* out = (float*)d_out;

    hipMemsetAsync(out, 0, sizeof(float), stream);
    k_fused<<<NBLOCKS, NTHREADS, 0, stream>>>(a, s, pe, ne, kp, out);
}